// Round 1
// baseline (365.546 us; speedup 1.0000x reference)
//
#include <hip/hip_runtime.h>
#include <hip/hip_bf16.h>

typedef unsigned short u16;
typedef unsigned int   u32;

typedef __bf16 bf16x8 __attribute__((ext_vector_type(8)));
typedef float  f32x4  __attribute__((ext_vector_type(4)));

#define MFMA16(A, B, C) __builtin_amdgcn_mfma_f32_16x16x32_bf16(A, B, C, 0, 0, 0)

static __device__ __forceinline__ u16 f2bf(float f) {
  union { float f; u32 u; } v; v.f = f;
  u32 r = v.u + 0x7fffu + ((v.u >> 16) & 1u);
  return (u16)(r >> 16);
}

static __device__ __forceinline__ void async16(const void* g, void* l) {
  __builtin_amdgcn_global_load_lds((const __attribute__((address_space(1))) void*)g,
                                   (__attribute__((address_space(3))) void*)l, 16, 0, 0);
}

// ---------------- x fp32 -> bf16 ----------------
__global__ __launch_bounds__(256) void cvtx_k(const float* __restrict__ x, u16* __restrict__ xb) {
  size_t i = ((size_t)blockIdx.x * 256 + threadIdx.x) * 4;
  float4 v = *(const float4*)(x + i);
  u32 lo = (u32)f2bf(v.x) | ((u32)f2bf(v.y) << 16);
  u32 hi = (u32)f2bf(v.z) | ((u32)f2bf(v.w) << 16);
  *(uint2*)(xb + i) = make_uint2(lo, hi);
}

// ---------------- W [K][N] fp32 -> WT [N][K] bf16 (tiled transpose) ----------------
__global__ __launch_bounds__(256) void wt_k(const float* __restrict__ Wq, const float* __restrict__ Wk,
                                            const float* __restrict__ Wv, const float* __restrict__ Wo,
                                            u16* __restrict__ WT) {
  const int z = blockIdx.z;
  const float* W = (z == 0) ? Wq : (z == 1) ? Wk : (z == 2) ? Wv : Wo;
  u16* out = WT + (size_t)z * 1048576;
  __shared__ float tile[32][33];
  const int tx = threadIdx.x & 31, ty = threadIdx.x >> 5;
  const int n0 = blockIdx.x * 32, k0 = blockIdx.y * 32;
#pragma unroll
  for (int i = 0; i < 4; i++)
    tile[ty + i * 8][tx] = W[(size_t)(k0 + ty + i * 8) * 1024 + n0 + tx];
  __syncthreads();
#pragma unroll
  for (int i = 0; i < 4; i++)
    out[(size_t)(n0 + ty + i * 8) * 1024 + k0 + tx] = f2bf(tile[tx][ty + i * 8]);
}

// ---------------- GEMM: [8192x1024] x WT[1024x1024]^T, m97 structure ----------------
// MODE 0: QKV projection. z=blockIdx.z in {0,1,2}; bf16 out in [B,H,T,d]; Q scaled by 0.125.
// MODE 1: out projection. fp32 out [8192][1024] + bias.
template <int MODE>
__global__ __launch_bounds__(256) void gemm_k(const u16* __restrict__ A, const u16* __restrict__ WTall,
                                              const float* __restrict__ b0, const float* __restrict__ b1,
                                              const float* __restrict__ b2,
                                              u16* __restrict__ outb, float* __restrict__ outf) {
  __shared__ u16 As[128 * 32];
  __shared__ u16 Bs[128 * 32];
  const int tid = threadIdx.x;
  const int m0 = blockIdx.x * 128;
  const int n0 = blockIdx.y * 128;
  const int z = blockIdx.z;
  const u16* WT = WTall + (size_t)(MODE == 0 ? z : 3) * 1048576;
  const float* bias = (MODE == 0) ? (z == 0 ? b0 : (z == 1 ? b1 : b2)) : b0;
  const float scl = (MODE == 0 && z == 0) ? 0.125f : 1.0f;

  const int lane = tid & 63;
  const int wid = tid >> 6;
  const int wr = wid >> 1, wc = wid & 1;
  const int g = lane >> 4, cc = lane & 15;

  const int srow = tid >> 2;          // 0..63
  const int scol = (tid & 3) * 8;     // 0,8,16,24
  const u16* gA0 = A + (size_t)(m0 + srow) * 1024 + scol;
  const u16* gA1 = A + (size_t)(m0 + srow + 64) * 1024 + scol;
  const u16* gB0 = WT + (size_t)(n0 + srow) * 1024 + scol;
  const u16* gB1 = WT + (size_t)(n0 + srow + 64) * 1024 + scol;
  u16* lA0 = &As[tid * 8]; u16* lA1 = &As[2048 + tid * 8];
  u16* lB0 = &Bs[tid * 8]; u16* lB1 = &Bs[2048 + tid * 8];

  f32x4 acc[4][4] = {};

  for (int kb = 0; kb < 1024; kb += 32) {
    __syncthreads();
    async16(gA0 + kb, lA0);
    async16(gA1 + kb, lA1);
    async16(gB0 + kb, lB0);
    async16(gB1 + kb, lB1);
    __syncthreads();
    bf16x8 af[4], bfv[4];
#pragma unroll
    for (int i = 0; i < 4; i++)
      af[i] = *(const bf16x8*)&As[(wr * 64 + i * 16 + cc) * 32 + g * 8];
#pragma unroll
    for (int i = 0; i < 4; i++)
      bfv[i] = *(const bf16x8*)&Bs[(wc * 64 + i * 16 + cc) * 32 + g * 8];
#pragma unroll
    for (int mi = 0; mi < 4; mi++)
#pragma unroll
      for (int ni = 0; ni < 4; ni++)
        acc[mi][ni] = MFMA16(af[mi], bfv[ni], acc[mi][ni]);
  }

#pragma unroll
  for (int mi = 0; mi < 4; mi++) {
#pragma unroll
    for (int ni = 0; ni < 4; ni++) {
      const int n = n0 + wc * 64 + ni * 16 + cc;
      const float bn = bias[n];
#pragma unroll
      for (int r = 0; r < 4; r++) {
        const int m = m0 + wr * 64 + mi * 16 + g * 4 + r;
        float val = acc[mi][ni][r] + bn;
        if (MODE == 0) {
          val *= scl;
          u16* o = outb + (size_t)z * 8388608;
          o[((size_t)((m >> 11) * 16 + (n >> 6)) * 2048 + (m & 2047)) * 64 + (n & 63)] = f2bf(val);
        } else {
          outf[(size_t)m * 1024 + n] = val;
        }
      }
    }
  }
}

// ---------------- Flash attention ----------------
// grid (32, 64): x = 64-row q tile, y = bh. 4 waves, 16 q-rows each.
// Swapped QK^T: S^T = mfma(K, Q); row-permuted K-frags so lane (g) holds s = 8g..8g+7,
// matching PV's A-operand layout for 16x16x32 directly (no cross-lane P move).
__global__ __launch_bounds__(256) void attn_k(const u16* __restrict__ Qg, const u16* __restrict__ Kg,
                                              const u16* __restrict__ Vg, u16* __restrict__ ctx) {
  __shared__ u16 Ks[64 * 72];
  __shared__ u16 VT[64 * 72];
  const int tid = threadIdx.x;
  const int lane = tid & 63;
  const int wid = tid >> 6;
  const int g = lane >> 4, cc = lane & 15;
  const int bh = blockIdx.y;
  const int q0 = blockIdx.x * 64 + wid * 16;
  const size_t base = (size_t)bh * 2048 * 64;

  bf16x8 qf[2];
#pragma unroll
  for (int c2 = 0; c2 < 2; c2++)
    qf[c2] = *(const bf16x8*)(Qg + base + (size_t)(q0 + cc) * 64 + c2 * 32 + g * 8);

  float m_run = -1e30f, l_run = 0.0f;
  f32x4 o[4] = {};

  const int srow = tid >> 3;        // 0..31
  const int sd0 = (tid & 7) * 8;    // 0..56

  for (int s0 = 0; s0 < 2048; s0 += 64) {
    __syncthreads();
#pragma unroll
    for (int p = 0; p < 2; p++) {
      const int row = srow + p * 32;
      int4 kv = *(const int4*)(Kg + base + (size_t)(s0 + row) * 64 + sd0);
      *(int4*)&Ks[row * 72 + sd0] = kv;
      int4 vv = *(const int4*)(Vg + base + (size_t)(s0 + row) * 64 + sd0);
      const u32 vx = (u32)vv.x, vy = (u32)vv.y, vz = (u32)vv.z, vw = (u32)vv.w;
      VT[(sd0 + 0) * 72 + row] = (u16)vx;  VT[(sd0 + 1) * 72 + row] = (u16)(vx >> 16);
      VT[(sd0 + 2) * 72 + row] = (u16)vy;  VT[(sd0 + 3) * 72 + row] = (u16)(vy >> 16);
      VT[(sd0 + 4) * 72 + row] = (u16)vz;  VT[(sd0 + 5) * 72 + row] = (u16)(vz >> 16);
      VT[(sd0 + 6) * 72 + row] = (u16)vw;  VT[(sd0 + 7) * 72 + row] = (u16)(vw >> 16);
    }
    __syncthreads();

#pragma unroll
    for (int sub = 0; sub < 2; sub++) {
      f32x4 st[2];
#pragma unroll
      for (int i = 0; i < 2; i++) {
        const int row = sub * 32 + 8 * (cc >> 2) + 4 * i + (cc & 3);  // permuted kv row
        bf16x8 k0 = *(const bf16x8*)&Ks[row * 72 + g * 8];
        bf16x8 k1 = *(const bf16x8*)&Ks[row * 72 + 32 + g * 8];
        f32x4 a = {};
        a = MFMA16(k0, qf[0], a);
        a = MFMA16(k1, qf[1], a);
        st[i] = a;
      }
      float pmax = -1e30f;
#pragma unroll
      for (int i = 0; i < 2; i++)
#pragma unroll
        for (int r = 0; r < 4; r++) pmax = fmaxf(pmax, st[i][r]);
      pmax = fmaxf(pmax, __shfl_xor(pmax, 16));
      pmax = fmaxf(pmax, __shfl_xor(pmax, 32));
      const float mnew = fmaxf(m_run, pmax);
      const float alpha = __expf(m_run - mnew);
      float p[8];
      float psum = 0.0f;
#pragma unroll
      for (int i = 0; i < 2; i++)
#pragma unroll
        for (int r = 0; r < 4; r++) {
          float pv = __expf(st[i][r] - mnew);
          p[i * 4 + r] = pv;
          psum += pv;
        }
      psum += __shfl_xor(psum, 16);
      psum += __shfl_xor(psum, 32);
      l_run = l_run * alpha + psum;
      m_run = mnew;
#pragma unroll
      for (int r = 0; r < 4; r++) {
        const float ar = __shfl(alpha, g * 4 + r);
#pragma unroll
        for (int t = 0; t < 4; t++) o[t][r] *= ar;
      }
      union { u32 u[4]; bf16x8 v; } pu;
#pragma unroll
      for (int j = 0; j < 4; j++)
        pu.u[j] = (u32)f2bf(p[2 * j]) | ((u32)f2bf(p[2 * j + 1]) << 16);
      const bf16x8 pf = pu.v;
#pragma unroll
      for (int t = 0; t < 4; t++) {
        bf16x8 vf = *(const bf16x8*)&VT[(t * 16 + cc) * 72 + sub * 32 + g * 8];
        o[t] = MFMA16(pf, vf, o[t]);
      }
    }
  }

  const int b = bh >> 4, h = bh & 15;
#pragma unroll
  for (int r = 0; r < 4; r++) {
    const float lr = __shfl(l_run, g * 4 + r);
    const float inv = 1.0f / lr;
    const int q = q0 + g * 4 + r;
#pragma unroll
    for (int t = 0; t < 4; t++) {
      const int dd = t * 16 + cc;
      ctx[((size_t)((b * 2048 + q) * 16 + h)) * 64 + dd] = f2bf(o[t][r] * inv);
    }
  }
}

extern "C" void kernel_launch(void* const* d_in, const int* in_sizes, int n_in,
                              void* d_out, int out_size, void* d_ws, size_t ws_size,
                              hipStream_t stream) {
  const float* x  = (const float*)d_in[0];
  const float* Wq = (const float*)d_in[1];
  const float* bq = (const float*)d_in[2];
  const float* Wk = (const float*)d_in[3];
  const float* bk = (const float*)d_in[4];
  const float* Wv = (const float*)d_in[5];
  const float* bv = (const float*)d_in[6];
  const float* Wo = (const float*)d_in[7];
  const float* bo = (const float*)d_in[8];
  float* out = (float*)d_out;

  char* w = (char*)d_ws;
  u16* xb   = (u16*)(w);                                        // 16 MB
  u16* WT   = (u16*)(w + (16u << 20));                          //  8 MB
  u16* QKV  = (u16*)(w + (24u << 20));                          // 48 MB (Q,K,V each 8388608 elems)
  u16* ctxb = (u16*)(w + (72u << 20));                          // 16 MB

  cvtx_k<<<dim3(8192), dim3(256), 0, stream>>>(x, xb);
  wt_k<<<dim3(32, 32, 4), dim3(256), 0, stream>>>(Wq, Wk, Wv, Wo, WT);
  gemm_k<0><<<dim3(64, 8, 3), dim3(256), 0, stream>>>(xb, WT, bq, bk, bv, QKV, nullptr);
  attn_k<<<dim3(32, 64), dim3(256), 0, stream>>>(QKV, QKV + 8388608, QKV + 2 * 8388608, ctxb);
  gemm_k<1><<<dim3(64, 8, 1), dim3(256), 0, stream>>>(ctxb, WT, bo, nullptr, nullptr, nullptr, out);
}

// Round 2
// 238.928 us; speedup vs baseline: 1.5299x; 1.5299x over previous
//
#include <hip/hip_runtime.h>
#include <hip/hip_bf16.h>

typedef unsigned short u16;
typedef unsigned int   u32;

typedef __bf16 bf16x8 __attribute__((ext_vector_type(8)));
typedef float  f32x4  __attribute__((ext_vector_type(4)));

#define MFMA16(A, B, C) __builtin_amdgcn_mfma_f32_16x16x32_bf16(A, B, C, 0, 0, 0)

static __device__ __forceinline__ u16 f2bf(float f) {
  union { float f; u32 u; } v; v.f = f;
  u32 r = v.u + 0x7fffu + ((v.u >> 16) & 1u);
  return (u16)(r >> 16);
}

// round-half-up pack of two f32 -> packed bf16x2 (3 VALU: 2 adds + 1 perm)
static __device__ __forceinline__ u32 pk2bf(float a, float b) {
  union { float f; u32 u; } x, y; x.f = a; y.f = b;
  return __builtin_amdgcn_perm(y.u + 0x8000u, x.u + 0x8000u, 0x07060302u);
}

static __device__ __forceinline__ void async16(const void* g, void* l) {
  __builtin_amdgcn_global_load_lds((const __attribute__((address_space(1))) void*)g,
                                   (__attribute__((address_space(3))) void*)l, 16, 0, 0);
}

// slot-swizzle involution (16B granularity) for 64x64-u16 LDS tiles
static __device__ __forceinline__ int permrow(int r) {
  return (r & 3) | (((r >> 3) & 1) << 2);
}

// ---------------- x fp32 -> bf16 ----------------
__global__ __launch_bounds__(256) void cvtx_k(const float* __restrict__ x, u16* __restrict__ xb) {
  size_t i = ((size_t)blockIdx.x * 256 + threadIdx.x) * 4;
  float4 v = *(const float4*)(x + i);
  u32 lo = (u32)f2bf(v.x) | ((u32)f2bf(v.y) << 16);
  u32 hi = (u32)f2bf(v.z) | ((u32)f2bf(v.w) << 16);
  *(uint2*)(xb + i) = make_uint2(lo, hi);
}

// ---------------- W [K][N] fp32 -> WT [N][K] bf16 (tiled transpose) ----------------
__global__ __launch_bounds__(256) void wt_k(const float* __restrict__ Wq, const float* __restrict__ Wk,
                                            const float* __restrict__ Wv, const float* __restrict__ Wo,
                                            u16* __restrict__ WT) {
  const int z = blockIdx.z;
  const float* W = (z == 0) ? Wq : (z == 1) ? Wk : (z == 2) ? Wv : Wo;
  u16* out = WT + (size_t)z * 1048576;
  __shared__ float tile[32][33];
  const int tx = threadIdx.x & 31, ty = threadIdx.x >> 5;
  const int n0 = blockIdx.x * 32, k0 = blockIdx.y * 32;
#pragma unroll
  for (int i = 0; i < 4; i++)
    tile[ty + i * 8][tx] = W[(size_t)(k0 + ty + i * 8) * 1024 + n0 + tx];
  __syncthreads();
#pragma unroll
  for (int i = 0; i < 4; i++)
    out[(size_t)(n0 + ty + i * 8) * 1024 + k0 + tx] = f2bf(tile[tx][ty + i * 8]);
}

// ---------------- GEMM: [8192x1024] x WT[1024x1024]^T, m97 structure ----------------
// MODE 0: QKV projection. z in {0,1,2}; Q scaled by 0.125, layouts:
//   Q,K -> [bh][t][d] ; V -> [bh][d][t]  (transposed, so attention stages it linearly)
// MODE 1: out projection. fp32 out [8192][1024] + bias.
template <int MODE>
__global__ __launch_bounds__(256) void gemm_k(const u16* __restrict__ A, const u16* __restrict__ WTall,
                                              const float* __restrict__ b0, const float* __restrict__ b1,
                                              const float* __restrict__ b2,
                                              u16* __restrict__ outb, float* __restrict__ outf) {
  __shared__ u16 As[128 * 32];
  __shared__ u16 Bs[128 * 32];
  const int tid = threadIdx.x;
  const int m0 = blockIdx.x * 128;
  const int n0 = blockIdx.y * 128;
  const int z = blockIdx.z;
  const u16* WT = WTall + (size_t)(MODE == 0 ? z : 3) * 1048576;
  const float* bias = (MODE == 0) ? (z == 0 ? b0 : (z == 1 ? b1 : b2)) : b0;
  const float scl = (MODE == 0 && z == 0) ? 0.125f : 1.0f;

  const int lane = tid & 63;
  const int wid = tid >> 6;
  const int wr = wid >> 1, wc = wid & 1;
  const int g = lane >> 4, cc = lane & 15;

  const int srow = tid >> 2;          // 0..63
  const int scol = (tid & 3) * 8;     // 0,8,16,24
  const u16* gA0 = A + (size_t)(m0 + srow) * 1024 + scol;
  const u16* gA1 = A + (size_t)(m0 + srow + 64) * 1024 + scol;
  const u16* gB0 = WT + (size_t)(n0 + srow) * 1024 + scol;
  const u16* gB1 = WT + (size_t)(n0 + srow + 64) * 1024 + scol;
  u16* lA0 = &As[tid * 8]; u16* lA1 = &As[2048 + tid * 8];
  u16* lB0 = &Bs[tid * 8]; u16* lB1 = &Bs[2048 + tid * 8];

  f32x4 acc[4][4] = {};

  for (int kb = 0; kb < 1024; kb += 32) {
    __syncthreads();
    async16(gA0 + kb, lA0);
    async16(gA1 + kb, lA1);
    async16(gB0 + kb, lB0);
    async16(gB1 + kb, lB1);
    __syncthreads();
    bf16x8 af[4], bfv[4];
#pragma unroll
    for (int i = 0; i < 4; i++)
      af[i] = *(const bf16x8*)&As[(wr * 64 + i * 16 + cc) * 32 + g * 8];
#pragma unroll
    for (int i = 0; i < 4; i++)
      bfv[i] = *(const bf16x8*)&Bs[(wc * 64 + i * 16 + cc) * 32 + g * 8];
#pragma unroll
    for (int mi = 0; mi < 4; mi++)
#pragma unroll
      for (int ni = 0; ni < 4; ni++)
        acc[mi][ni] = MFMA16(af[mi], bfv[ni], acc[mi][ni]);
  }

#pragma unroll
  for (int mi = 0; mi < 4; mi++) {
#pragma unroll
    for (int ni = 0; ni < 4; ni++) {
      const int n = n0 + wc * 64 + ni * 16 + cc;
      const float bn = bias[n];
      const int mb = m0 + wr * 64 + mi * 16 + g * 4;
      if (MODE == 0) {
        u16* o = outb + (size_t)z * 8388608;
        if (z == 2) {
          // V^T: [bh][d][t] ; 4 consecutive t -> one uint2 store
          u16 h[4];
#pragma unroll
          for (int r = 0; r < 4; r++) h[r] = f2bf(acc[mi][ni][r] + bn);
          const size_t idx = ((size_t)(((mb >> 11) * 16 + (n >> 6)) * 64 + (n & 63))) * 2048 + (mb & 2047);
          *(uint2*)&o[idx] = make_uint2((u32)h[0] | ((u32)h[1] << 16), (u32)h[2] | ((u32)h[3] << 16));
        } else {
#pragma unroll
          for (int r = 0; r < 4; r++) {
            const int m = mb + r;
            const float val = (acc[mi][ni][r] + bn) * scl;
            o[((size_t)((m >> 11) * 16 + (n >> 6)) * 2048 + (m & 2047)) * 64 + (n & 63)] = f2bf(val);
          }
        }
      } else {
#pragma unroll
        for (int r = 0; r < 4; r++)
          outf[(size_t)(mb + r) * 1024 + n] = acc[mi][ni][r] + bn;
      }
    }
  }
}

// ---------------- Flash attention ----------------
// grid (32, 64): x = 64-row q tile, y = bh. 4 waves, 16 q-rows each.
// Swapped QK^T: S^T = mfma(K, Q) with row-permuted K-frags so the S^T register
// layout lands exactly in the PV A-operand layout (no cross-lane P move).
// K [bh][t][d] and V^T [bh][d][t] staged via global_load_lds into linear 64x64
// LDS tiles with an XOR slot-swizzle applied on the global SOURCE address and
// again on every read (conflict-free b128 reads). Double-buffered 2-phase.
// Row sums come from an extra ones-column MFMA (o[4]); defer-max THR=8.
__global__ __launch_bounds__(256) void attn_k(const u16* __restrict__ Qg, const u16* __restrict__ Kg,
                                              const u16* __restrict__ Vtg, u16* __restrict__ ctx) {
  __shared__ u16 Ks[2][4096];
  __shared__ u16 Vs[2][4096];
  const int tid = threadIdx.x;
  const int lane = tid & 63;
  const int wid = tid >> 6;
  const int g = lane >> 4, cc = lane & 15;
  const int a_ = cc >> 2, b_ = cc & 3;
  const int bh = blockIdx.y;
  const int q0 = blockIdx.x * 64 + wid * 16;
  const size_t base = (size_t)bh * 131072;  // 2048*64

  bf16x8 qf[2];
#pragma unroll
  for (int c2 = 0; c2 < 2; c2++)
    qf[c2] = *(const bf16x8*)(Qg + base + (size_t)(q0 + cc) * 64 + c2 * 32 + g * 8);

  bf16x8 vone;
#pragma unroll
  for (int j = 0; j < 8; j++) vone[j] = (__bf16)1.0f;

  float m_run = -30000.0f;
  f32x4 o[5] = {};  // o[0..3]: output d-frags; o[4]: row sums (ones column)

  // staging: thread covers rows (tid>>3) and (tid>>3)+32, 16B slot (tid&7)
  const int r0 = tid >> 3, r1 = r0 + 32;
  const int slot = tid & 7;
  const int sp0 = slot ^ permrow(r0), sp1 = slot ^ permrow(r1);
  const u16* kS0 = Kg + base + (size_t)r0 * 64 + (sp0 << 3);
  const u16* kS1 = Kg + base + (size_t)r1 * 64 + (sp1 << 3);
  const u16* vS0 = Vtg + base + (size_t)r0 * 2048 + (sp0 << 3);
  const u16* vS1 = Vtg + base + (size_t)r1 * 2048 + (sp1 << 3);

  int buf = 0;
  // stage tile 0
  async16(kS0, &Ks[0][tid * 8]);
  async16(kS1, &Ks[0][tid * 8 + 2048]);
  async16(vS0, &Vs[0][tid * 8]);
  async16(vS1, &Vs[0][tid * 8 + 2048]);

  for (int it = 0; it < 32; ++it) {
    __syncthreads();  // stage(it) landed; all reads of buf^1 done
    if (it + 1 < 32) {
      const size_t ko = (size_t)(it + 1) * 4096;  // 64 rows * 64
      const size_t vo = (size_t)(it + 1) * 64;
      const int nb = buf ^ 1;
      async16(kS0 + ko, &Ks[nb][tid * 8]);
      async16(kS1 + ko, &Ks[nb][tid * 8 + 2048]);
      async16(vS0 + vo, &Vs[nb][tid * 8]);
      async16(vS1 + vo, &Vs[nb][tid * 8 + 2048]);
    }
    const u16* KL = &Ks[buf][0];
    const u16* VL = &Vs[buf][0];

#pragma unroll
    for (int sub = 0; sub < 2; ++sub) {
      f32x4 st[2];
#pragma unroll
      for (int i = 0; i < 2; ++i) {
        const int row = sub * 32 + 8 * a_ + 4 * i + b_;  // permuted kv row
        const int sl = g ^ permrow(row);
        bf16x8 k0 = *(const bf16x8*)&KL[row * 64 + (sl << 3)];
        bf16x8 k1 = *(const bf16x8*)&KL[row * 64 + ((sl ^ 4) << 3)];
        f32x4 a = {};
        a = MFMA16(k0, qf[0], a);
        a = MFMA16(k1, qf[1], a);
        st[i] = a;
      }
      // local max over this lane's 8 scores
      float pm = fmaxf(fmaxf(fmaxf(st[0][0], st[0][1]), fmaxf(st[0][2], st[0][3])),
                       fmaxf(fmaxf(st[1][0], st[1][1]), fmaxf(st[1][2], st[1][3])));
      if (!__all(pm <= m_run + 8.0f)) {
        // rescale path (rare after first tile)
        pm = fmaxf(pm, __shfl_xor(pm, 16));
        pm = fmaxf(pm, __shfl_xor(pm, 32));
        const float mnew = fmaxf(m_run, pm);
        const float alpha = __expf(m_run - mnew);
#pragma unroll
        for (int r = 0; r < 4; r++) {
          const float ar = __shfl(alpha, g * 4 + r);
#pragma unroll
          for (int t = 0; t < 5; t++) o[t][r] *= ar;
        }
        m_run = mnew;
      }
      float e[8];
#pragma unroll
      for (int i = 0; i < 2; ++i)
#pragma unroll
        for (int r = 0; r < 4; ++r) e[i * 4 + r] = __expf(st[i][r] - m_run);
      union { u32 u[4]; bf16x8 v; } pu;
#pragma unroll
      for (int j = 0; j < 4; ++j) pu.u[j] = pk2bf(e[2 * j], e[2 * j + 1]);
      const bf16x8 pf = pu.v;
#pragma unroll
      for (int t = 0; t < 4; ++t) {
        const int row = t * 16 + cc;
        const int sl = (sub * 4 + g) ^ permrow(row);
        bf16x8 vf = *(const bf16x8*)&VL[row * 64 + (sl << 3)];
        o[t] = MFMA16(pf, vf, o[t]);
      }
      o[4] = MFMA16(pf, vone, o[4]);  // row sums
    }
    buf ^= 1;
  }

  const int b = bh >> 4, h = bh & 15;
#pragma unroll
  for (int r = 0; r < 4; r++) {
    const float inv = __builtin_amdgcn_rcpf(o[4][r]);  // l for q row g*4+r, same lane
    const int q = q0 + g * 4 + r;
#pragma unroll
    for (int t = 0; t < 4; t++) {
      const int dd = t * 16 + cc;
      ctx[((size_t)((b * 2048 + q) * 16 + h)) * 64 + dd] = f2bf(o[t][r] * inv);
    }
  }
}

extern "C" void kernel_launch(void* const* d_in, const int* in_sizes, int n_in,
                              void* d_out, int out_size, void* d_ws, size_t ws_size,
                              hipStream_t stream) {
  const float* x  = (const float*)d_in[0];
  const float* Wq = (const float*)d_in[1];
  const float* bq = (const float*)d_in[2];
  const float* Wk = (const float*)d_in[3];
  const float* bk = (const float*)d_in[4];
  const float* Wv = (const float*)d_in[5];
  const float* bv = (const float*)d_in[6];
  const float* Wo = (const float*)d_in[7];
  const float* bo = (const float*)d_in[8];
  float* out = (float*)d_out;

  char* w = (char*)d_ws;
  u16* xb   = (u16*)(w);                // 16 MB
  u16* WT   = (u16*)(w + (16u << 20));  //  8 MB
  u16* QKV  = (u16*)(w + (24u << 20));  // 48 MB (Q,K: [bh][t][d]; V: [bh][d][t])
  u16* ctxb = (u16*)(w + (72u << 20));  // 16 MB

  cvtx_k<<<dim3(8192), dim3(256), 0, stream>>>(x, xb);
  wt_k<<<dim3(32, 32, 4), dim3(256), 0, stream>>>(Wq, Wk, Wv, Wo, WT);
  gemm_k<0><<<dim3(64, 8, 3), dim3(256), 0, stream>>>(xb, WT, bq, bk, bv, QKV, nullptr);
  attn_k<<<dim3(32, 64), dim3(256), 0, stream>>>(QKV, QKV + 8388608, QKV + 2 * 8388608, ctxb);
  gemm_k<1><<<dim3(64, 8, 1), dim3(256), 0, stream>>>(ctxb, WT, bo, nullptr, nullptr, nullptr, out);
}

// Round 3
// 217.585 us; speedup vs baseline: 1.6800x; 1.0981x over previous
//
#include <hip/hip_runtime.h>
#include <hip/hip_bf16.h>

typedef unsigned short u16;
typedef unsigned int   u32;

typedef __bf16 bf16x8 __attribute__((ext_vector_type(8)));
typedef float  f32x4  __attribute__((ext_vector_type(4)));

#define MFMA16(A, B, C) __builtin_amdgcn_mfma_f32_16x16x32_bf16(A, B, C, 0, 0, 0)

static __device__ __forceinline__ u16 f2bf(float f) {
  union { float f; u32 u; } v; v.f = f;
  u32 r = v.u + 0x7fffu + ((v.u >> 16) & 1u);
  return (u16)(r >> 16);
}

static __device__ __forceinline__ float exp2a(float x) {  // 2^x, raw v_exp_f32
  float r; asm("v_exp_f32 %0, %1" : "=v"(r) : "v"(x)); return r;
}
static __device__ __forceinline__ float max3f(float a, float b, float c) {
  float r; asm("v_max3_f32 %0, %1, %2, %3" : "=v"(r) : "v"(a), "v"(b), "v"(c)); return r;
}
static __device__ __forceinline__ u32 cvtpk(float lo, float hi) {  // {bf16(lo), bf16(hi)}
  u32 r; asm("v_cvt_pk_bf16_f32 %0, %1, %2" : "=v"(r) : "v"(lo), "v"(hi)); return r;
}

static __device__ __forceinline__ void async16(const void* g, void* l) {
  __builtin_amdgcn_global_load_lds((const __attribute__((address_space(1))) void*)g,
                                   (__attribute__((address_space(3))) void*)l, 16, 0, 0);
}

// slot-swizzle involution (16B granularity) for 64x64-u16 LDS tiles
static __device__ __forceinline__ int permrow(int r) {
  return (r & 3) | (((r >> 3) & 1) << 2);
}

// ---------------- x fp32 -> bf16 ----------------
__global__ __launch_bounds__(256) void cvtx_k(const float* __restrict__ x, u16* __restrict__ xb) {
  size_t i = ((size_t)blockIdx.x * 256 + threadIdx.x) * 4;
  float4 v = *(const float4*)(x + i);
  u32 lo = (u32)f2bf(v.x) | ((u32)f2bf(v.y) << 16);
  u32 hi = (u32)f2bf(v.z) | ((u32)f2bf(v.w) << 16);
  *(uint2*)(xb + i) = make_uint2(lo, hi);
}

// ---------------- W [K][N] fp32 -> WT [N][K] bf16 (tiled transpose) ----------------
__global__ __launch_bounds__(256) void wt_k(const float* __restrict__ Wq, const float* __restrict__ Wk,
                                            const float* __restrict__ Wv, const float* __restrict__ Wo,
                                            u16* __restrict__ WT) {
  const int z = blockIdx.z;
  const float* W = (z == 0) ? Wq : (z == 1) ? Wk : (z == 2) ? Wv : Wo;
  u16* out = WT + (size_t)z * 1048576;
  __shared__ float tile[32][33];
  const int tx = threadIdx.x & 31, ty = threadIdx.x >> 5;
  const int n0 = blockIdx.x * 32, k0 = blockIdx.y * 32;
#pragma unroll
  for (int i = 0; i < 4; i++)
    tile[ty + i * 8][tx] = W[(size_t)(k0 + ty + i * 8) * 1024 + n0 + tx];
  __syncthreads();
#pragma unroll
  for (int i = 0; i < 4; i++)
    out[(size_t)(n0 + ty + i * 8) * 1024 + k0 + tx] = f2bf(tile[tx][ty + i * 8]);
}

// ---------------- GEMM: [8192x1024] x WT[1024x1024]^T, m97 structure ----------------
// MODE 0: QKV projection. z in {0,1,2}; Q scaled by 0.125*log2(e) (softmax uses exp2),
//   layouts: Q,K -> [bh][t][d] ; V -> [bh][d][t].
// MODE 1: out projection. fp32 out [8192][1024] + bias.
template <int MODE>
__global__ __launch_bounds__(256) void gemm_k(const u16* __restrict__ A, const u16* __restrict__ WTall,
                                              const float* __restrict__ b0, const float* __restrict__ b1,
                                              const float* __restrict__ b2,
                                              u16* __restrict__ outb, float* __restrict__ outf) {
  __shared__ u16 As[128 * 32];
  __shared__ u16 Bs[128 * 32];
  const int tid = threadIdx.x;
  const int m0 = blockIdx.x * 128;
  const int n0 = blockIdx.y * 128;
  const int z = blockIdx.z;
  const u16* WT = WTall + (size_t)(MODE == 0 ? z : 3) * 1048576;
  const float* bias = (MODE == 0) ? (z == 0 ? b0 : (z == 1 ? b1 : b2)) : b0;
  const float scl = (MODE == 0 && z == 0) ? 0.18033688011112042f : 1.0f;  // 0.125*log2e

  const int lane = tid & 63;
  const int wid = tid >> 6;
  const int wr = wid >> 1, wc = wid & 1;
  const int g = lane >> 4, cc = lane & 15;

  const int srow = tid >> 2;          // 0..63
  const int scol = (tid & 3) * 8;     // 0,8,16,24
  const u16* gA0 = A + (size_t)(m0 + srow) * 1024 + scol;
  const u16* gA1 = A + (size_t)(m0 + srow + 64) * 1024 + scol;
  const u16* gB0 = WT + (size_t)(n0 + srow) * 1024 + scol;
  const u16* gB1 = WT + (size_t)(n0 + srow + 64) * 1024 + scol;
  u16* lA0 = &As[tid * 8]; u16* lA1 = &As[2048 + tid * 8];
  u16* lB0 = &Bs[tid * 8]; u16* lB1 = &Bs[2048 + tid * 8];

  f32x4 acc[4][4] = {};

  for (int kb = 0; kb < 1024; kb += 32) {
    __syncthreads();
    async16(gA0 + kb, lA0);
    async16(gA1 + kb, lA1);
    async16(gB0 + kb, lB0);
    async16(gB1 + kb, lB1);
    __syncthreads();
    bf16x8 af[4], bfv[4];
#pragma unroll
    for (int i = 0; i < 4; i++)
      af[i] = *(const bf16x8*)&As[(wr * 64 + i * 16 + cc) * 32 + g * 8];
#pragma unroll
    for (int i = 0; i < 4; i++)
      bfv[i] = *(const bf16x8*)&Bs[(wc * 64 + i * 16 + cc) * 32 + g * 8];
#pragma unroll
    for (int mi = 0; mi < 4; mi++)
#pragma unroll
      for (int ni = 0; ni < 4; ni++)
        acc[mi][ni] = MFMA16(af[mi], bfv[ni], acc[mi][ni]);
  }

#pragma unroll
  for (int mi = 0; mi < 4; mi++) {
#pragma unroll
    for (int ni = 0; ni < 4; ni++) {
      const int n = n0 + wc * 64 + ni * 16 + cc;
      const float bn = bias[n];
      const int mb = m0 + wr * 64 + mi * 16 + g * 4;
      if (MODE == 0) {
        u16* o = outb + (size_t)z * 8388608;
        if (z == 2) {
          // V^T: [bh][d][t] ; 4 consecutive t -> one uint2 store
          u16 h[4];
#pragma unroll
          for (int r = 0; r < 4; r++) h[r] = f2bf(acc[mi][ni][r] + bn);
          const size_t idx = ((size_t)(((mb >> 11) * 16 + (n >> 6)) * 64 + (n & 63))) * 2048 + (mb & 2047);
          *(uint2*)&o[idx] = make_uint2((u32)h[0] | ((u32)h[1] << 16), (u32)h[2] | ((u32)h[3] << 16));
        } else {
#pragma unroll
          for (int r = 0; r < 4; r++) {
            const int m = mb + r;
            const float val = (acc[mi][ni][r] + bn) * scl;
            o[((size_t)((m >> 11) * 16 + (n >> 6)) * 2048 + (m & 2047)) * 64 + (n & 63)] = f2bf(val);
          }
        }
      } else {
#pragma unroll
        for (int r = 0; r < 4; r++)
          outf[(size_t)(mb + r) * 1024 + n] = acc[mi][ni][r] + bn;
      }
    }
  }
}

// ---------------- Flash attention ----------------
// grid (16, 64): x = 128-row q tile, y = bh. 4 waves; each wave owns TWO 16-row
// q groups (q0..q0+15 and q0+64..q0+79) so each K/V LDS read feeds 2x the MFMA.
// Swapped QK^T with row-permuted K-frags: lane (g,cc) holds S[kv=sub*32+8g+4i+r][q0+cc],
// which IS the PV A-operand layout. XOR slot-swizzle on staging source + reads
// (conflict-free). Tile loop unrolled by 2 -> compile-time LDS buffer bases.
// Softmax in log2 domain (Q pre-scaled by log2e); row sums via ones-column MFMA.
#define SOFTMAX_GRP(ST, MRUN, O, PF)                                          \
  {                                                                           \
    float pm_ = max3f(max3f(ST[0][0], ST[0][1], ST[0][2]),                    \
                      max3f(ST[0][3], ST[1][0], ST[1][1]),                    \
                      fmaxf(ST[1][2], ST[1][3]));                             \
    if (!__all(pm_ <= MRUN + 8.0f)) {                                         \
      pm_ = fmaxf(pm_, __shfl_xor(pm_, 16));                                  \
      pm_ = fmaxf(pm_, __shfl_xor(pm_, 32));                                  \
      const float mn_ = fmaxf(MRUN, pm_);                                     \
      const float al_ = exp2a(MRUN - mn_);                                    \
      _Pragma("unroll")                                                       \
      for (int r_ = 0; r_ < 4; ++r_) {                                        \
        const float ar_ = __shfl(al_, g * 4 + r_);                            \
        _Pragma("unroll")                                                     \
        for (int t_ = 0; t_ < 5; ++t_) O[t_][r_] *= ar_;                      \
      }                                                                       \
      MRUN = mn_;                                                             \
    }                                                                         \
    const float e0_ = exp2a(ST[0][0] - MRUN), e1_ = exp2a(ST[0][1] - MRUN);   \
    const float e2_ = exp2a(ST[0][2] - MRUN), e3_ = exp2a(ST[0][3] - MRUN);   \
    const float e4_ = exp2a(ST[1][0] - MRUN), e5_ = exp2a(ST[1][1] - MRUN);   \
    const float e6_ = exp2a(ST[1][2] - MRUN), e7_ = exp2a(ST[1][3] - MRUN);   \
    union { u32 u[4]; bf16x8 v; } pu_;                                        \
    pu_.u[0] = cvtpk(e0_, e1_); pu_.u[1] = cvtpk(e2_, e3_);                   \
    pu_.u[2] = cvtpk(e4_, e5_); pu_.u[3] = cvtpk(e6_, e7_);                   \
    PF = pu_.v;                                                               \
  }

#define COMPUTE(BUF)                                                          \
  _Pragma("unroll")                                                           \
  for (int sub = 0; sub < 2; ++sub) {                                         \
    f32x4 stA[2], stB[2];                                                     \
    _Pragma("unroll")                                                         \
    for (int i = 0; i < 2; ++i) {                                             \
      const int row_ = sub * 32 + 8 * a_ + 4 * i + b_;                        \
      const int sl_ = g ^ permrow(row_);                                      \
      bf16x8 k0 = *(const bf16x8*)&Ks[BUF][row_ * 64 + (sl_ << 3)];           \
      bf16x8 k1 = *(const bf16x8*)&Ks[BUF][row_ * 64 + ((sl_ ^ 4) << 3)];     \
      f32x4 t0 = {};                                                          \
      t0 = MFMA16(k0, qfA[0], t0); t0 = MFMA16(k1, qfA[1], t0); stA[i] = t0;  \
      f32x4 t1 = {};                                                          \
      t1 = MFMA16(k0, qfB[0], t1); t1 = MFMA16(k1, qfB[1], t1); stB[i] = t1;  \
    }                                                                         \
    bf16x8 pfA, pfB;                                                          \
    SOFTMAX_GRP(stA, mA, oA, pfA);                                            \
    SOFTMAX_GRP(stB, mB, oB, pfB);                                            \
    _Pragma("unroll")                                                         \
    for (int t = 0; t < 4; ++t) {                                             \
      const int vrow_ = t * 16 + cc;                                          \
      const int sv_ = (sub * 4 + g) ^ permrow(vrow_);                         \
      bf16x8 vf = *(const bf16x8*)&Vs[BUF][vrow_ * 64 + (sv_ << 3)];          \
      oA[t] = MFMA16(pfA, vf, oA[t]);                                         \
      oB[t] = MFMA16(pfB, vf, oB[t]);                                         \
    }                                                                         \
    oA[4] = MFMA16(pfA, vone, oA[4]);                                         \
    oB[4] = MFMA16(pfB, vone, oB[4]);                                         \
  }

#define STEP(BUF, IT)                                                         \
  {                                                                           \
    __syncthreads();                                                          \
    if ((IT) < 31) {                                                          \
      const size_t ko_ = (size_t)((IT) + 1) * 4096;                           \
      const size_t vo_ = (size_t)((IT) + 1) * 64;                             \
      async16(kS0 + ko_, &Ks[BUF ^ 1][tid * 8]);                              \
      async16(kS1 + ko_, &Ks[BUF ^ 1][tid * 8 + 2048]);                       \
      async16(vS0 + vo_, &Vs[BUF ^ 1][tid * 8]);                              \
      async16(vS1 + vo_, &Vs[BUF ^ 1][tid * 8 + 2048]);                       \
    }                                                                         \
    COMPUTE(BUF)                                                              \
  }

__global__ __launch_bounds__(256) void attn_k(const u16* __restrict__ Qg, const u16* __restrict__ Kg,
                                              const u16* __restrict__ Vtg, u16* __restrict__ ctx) {
  __shared__ u16 Ks[2][4096];
  __shared__ u16 Vs[2][4096];
  const int tid = threadIdx.x;
  const int lane = tid & 63;
  const int wid = tid >> 6;
  const int g = lane >> 4, cc = lane & 15;
  const int a_ = cc >> 2, b_ = cc & 3;
  const int bh = blockIdx.y;
  const int q0 = blockIdx.x * 128 + wid * 16;
  const size_t base = (size_t)bh * 131072;  // 2048*64

  bf16x8 qfA[2], qfB[2];
#pragma unroll
  for (int c2 = 0; c2 < 2; c2++) {
    qfA[c2] = *(const bf16x8*)(Qg + base + (size_t)(q0 + cc) * 64 + c2 * 32 + g * 8);
    qfB[c2] = *(const bf16x8*)(Qg + base + (size_t)(q0 + 64 + cc) * 64 + c2 * 32 + g * 8);
  }

  bf16x8 vone;
#pragma unroll
  for (int j = 0; j < 8; j++) vone[j] = (__bf16)1.0f;

  float mA = -30000.0f, mB = -30000.0f;
  f32x4 oA[5] = {}, oB[5] = {};  // [0..3]: output d-frags; [4]: row sums

  // staging: thread covers rows (tid>>3) and (tid>>3)+32, 16B slot (tid&7)
  const int r0 = tid >> 3, r1 = r0 + 32;
  const int slot = tid & 7;
  const int sp0 = slot ^ permrow(r0), sp1 = slot ^ permrow(r1);
  const u16* kS0 = Kg + base + (size_t)r0 * 64 + (sp0 << 3);
  const u16* kS1 = Kg + base + (size_t)r1 * 64 + (sp1 << 3);
  const u16* vS0 = Vtg + base + (size_t)r0 * 2048 + (sp0 << 3);
  const u16* vS1 = Vtg + base + (size_t)r1 * 2048 + (sp1 << 3);

  // stage tile 0 into buf 0
  async16(kS0, &Ks[0][tid * 8]);
  async16(kS1, &Ks[0][tid * 8 + 2048]);
  async16(vS0, &Vs[0][tid * 8]);
  async16(vS1, &Vs[0][tid * 8 + 2048]);

  for (int it = 0; it < 32; it += 2) {
    STEP(0, it)
    STEP(1, it + 1)
  }

  const int b = bh >> 4, h = bh & 15;
#pragma unroll
  for (int r = 0; r < 4; r++) {
    {
      const float inv = __builtin_amdgcn_rcpf(oA[4][r]);
      const int q = q0 + g * 4 + r;
#pragma unroll
      for (int t = 0; t < 4; t++)
        ctx[((size_t)((b * 2048 + q) * 16 + h)) * 64 + t * 16 + cc] = f2bf(oA[t][r] * inv);
    }
    {
      const float inv = __builtin_amdgcn_rcpf(oB[4][r]);
      const int q = q0 + 64 + g * 4 + r;
#pragma unroll
      for (int t = 0; t < 4; t++)
        ctx[((size_t)((b * 2048 + q) * 16 + h)) * 64 + t * 16 + cc] = f2bf(oB[t][r] * inv);
    }
  }
}

extern "C" void kernel_launch(void* const* d_in, const int* in_sizes, int n_in,
                              void* d_out, int out_size, void* d_ws, size_t ws_size,
                              hipStream_t stream) {
  const float* x  = (const float*)d_in[0];
  const float* Wq = (const float*)d_in[1];
  const float* bq = (const float*)d_in[2];
  const float* Wk = (const float*)d_in[3];
  const float* bk = (const float*)d_in[4];
  const float* Wv = (const float*)d_in[5];
  const float* bv = (const float*)d_in[6];
  const float* Wo = (const float*)d_in[7];
  const float* bo = (const float*)d_in[8];
  float* out = (float*)d_out;

  char* w = (char*)d_ws;
  u16* xb   = (u16*)(w);                // 16 MB
  u16* WT   = (u16*)(w + (16u << 20));  //  8 MB
  u16* QKV  = (u16*)(w + (24u << 20));  // 48 MB (Q,K: [bh][t][d]; V: [bh][d][t])
  u16* ctxb = (u16*)(w + (72u << 20));  // 16 MB

  cvtx_k<<<dim3(8192), dim3(256), 0, stream>>>(x, xb);
  wt_k<<<dim3(32, 32, 4), dim3(256), 0, stream>>>(Wq, Wk, Wv, Wo, WT);
  gemm_k<0><<<dim3(64, 8, 3), dim3(256), 0, stream>>>(xb, WT, bq, bk, bv, QKV, nullptr);
  attn_k<<<dim3(16, 64), dim3(256), 0, stream>>>(QKV, QKV + 8388608, QKV + 2 * 8388608, ctxb);
  gemm_k<1><<<dim3(64, 8, 1), dim3(256), 0, stream>>>(ctxb, WT, bo, nullptr, nullptr, nullptr, out);
}